// Round 1
// baseline (339.836 us; speedup 1.0000x reference)
//
#include <hip/hip_runtime.h>

// RRSVM rank-weighted pooling, 3x3 / stride 2 / pad 1.
// x: [B=32, C=64, H=112, W=112] fp32;  s: [C, 3, 3] fp32
// out0: [B,C,56,56] fp32 ; out1: order [B,C,56,56,9] written as fp32.
//
// R6: persistent-plane blocks + 2-phase software pipeline (T14 async-stage
// split). One block per (b,c) plane loops over the 14 ho-tiles; tile t+1's
// global loads are issued into registers BEFORE tile t's sort, and the
// vmcnt wait lands at the ds_write after the compute phase. Keeps 8
// blocks/CU x 4KB reads permanently in flight (vs ~1 block's worth in the
// one-shot R5 version), so the ~20us of sort VALU hides under the ~58us
// memory stream instead of adding to it.
// Sort / gather / writeback logic identical to verified R5.

typedef float nfloat4 __attribute__((ext_vector_type(4)));

constexpr int B  = 32;
constexpr int C  = 64;
constexpr int H  = 112;
constexpr int W  = 112;
constexpr int HO = 56;
constexpr int WO = 56;
constexpr int KK = 9;
constexpr int NPIX = HO * WO;          // 3136 windows per (b,c) plane
constexpr int BLK  = 256;
constexpr int LROW = 128;              // LDS row stride (floats)
constexpr int RPT  = 4;                // window-rows per tile
constexpr int IR   = 2 * RPT + 1;      // input rows staged per tile = 9
constexpr int NT   = HO / RPT;         // 14 tiles per plane

__global__ __launch_bounds__(BLK, 8) void rrsvm_kernel(
    const float* __restrict__ x, const float* __restrict__ s,
    float* __restrict__ out, float* __restrict__ order)
{
    __shared__ float lx[2][IR * LROW];         // 2 x 4608 B, double-buffered
    __shared__ float lorder[RPT * WO * KK];    // 8064 B

    const int plane = blockIdx.x;              // b*C + c (block-uniform)
    const int tid   = threadIdx.x;
    const int w     = tid >> 6;                // wave id 0..3 -> window-row
    const int lane  = tid & 63;                // lane -> window-col (56 live)
    const int c     = plane & (C - 1);

    const float* xp = x + (size_t)plane * (H * W);

    // Fixed staging task per thread: row sr (0..8), float4-col scc (0..27).
    const bool stager = (tid < IR * (W / 4));  // 252 float4 tasks
    const int  sr  = tid / (W / 4);
    const int  scc = tid - sr * (W / 4);

    // Per-channel rank weights: uniform address -> scalar loads (SGPRs).
    float wts[KK];
#pragma unroll
    for (int k = 0; k < KK; ++k) wts[k] = s[c * KK + k];

    // Logical col -1 = pad zero, written once per buffer (never overwritten).
    if (tid < 2 * IR) {
        const int bi = tid / IR, r = tid - bi * IR;
        lx[bi][r * LROW] = 0.0f;
    }

    // ---- Prologue: stage tile 0 (global rows -1..7, shifted +1 in LDS).
    if (stager) {
        const int grow = sr - 1;               // -1..7 ; only r==0 is OOB
        nfloat4 val = (nfloat4)0.0f;
        if ((unsigned)grow < (unsigned)H)
            val = *(const nfloat4*)(xp + grow * W + 4 * scc);
        float* dst = &lx[0][sr * LROW + 1 + 4 * scc];
        dst[0] = val.x; dst[1] = val.y; dst[2] = val.z; dst[3] = val.w;
    }
    __syncthreads();

    const bool live = (lane < WO);
    const int  lc   = live ? lane : 0;

    for (int t = 0; t < NT; ++t) {
        // ---- Issue tile t+1's loads NOW; regs stay live across the sort,
        // vmcnt wait happens at the ds_write after the compute phase.
        nfloat4 nval = (nfloat4)0.0f;
        if (t + 1 < NT && stager) {
            const int grow = 8 * (t + 1) - 1 + sr;   // 7..111, always in range
            nval = *(const nfloat4*)(xp + grow * W + 4 * scc);
        }

        // ---- Gather window from current LDS buffer.
        const float* lxt = lx[t & 1];
        float v[KK];
        float fid[KK];
#pragma unroll
        for (int dy = 0; dy < 3; ++dy)
#pragma unroll
            for (int dx = 0; dx < 3; ++dx) {
                const int k = dy * 3 + dx;
                v[k]   = lxt[(2 * w + dy) * LROW + 2 * lc + dx];
                fid[k] = (float)k;             // compile-time constant
            }

        // ---- Sort descending by value; exact tie -> smaller index first.
        auto CE = [&](int a, int b) {
            const float va = v[a],   vb = v[b];
            const float fa = fid[a], fb = fid[b];
            const bool sw = (va < vb) || ((va == vb) && (fa > fb));
            v[a]   = sw ? vb : va;  v[b]   = sw ? va : vb;
            fid[a] = sw ? fb : fa;  fid[b] = sw ? fa : fb;
        };
        // Batcher odd-even mergesort on 0..7 (19 CEs) + insertion of 8 (8 CEs).
        CE(0,1); CE(2,3); CE(4,5); CE(6,7);
        CE(0,2); CE(1,3); CE(4,6); CE(5,7);
        CE(1,2); CE(5,6);
        CE(0,4); CE(1,5); CE(2,6); CE(3,7);
        CE(2,4); CE(3,5);
        CE(1,2); CE(3,4); CE(5,6);
        CE(7,8); CE(6,7); CE(5,6); CE(4,5); CE(3,4); CE(2,3); CE(1,2); CE(0,1);

        // ---- Weighted sum with per-channel rank weights.
        float acc = 0.0f;
#pragma unroll
        for (int k = 0; k < KK; ++k) acc = fmaf(v[k], wts[k], acc);

        const int ho = t * RPT + w;
        if (live) {
            __builtin_nontemporal_store(
                acc, out + (size_t)plane * NPIX + ho * WO + lane);
            const int widx = w * WO + lane;    // window within tile, 0..223
#pragma unroll
            for (int k = 0; k < KK; ++k)
                lorder[widx * KK + k] = fid[k];    // stride 9 -> 2-way, free
        }
        __syncthreads();   // A: lorder complete (gathers of buf[t&1] done too)

        // ---- Coalesced nontemporal float4 writeback of this tile's order.
        nfloat4* __restrict__ ob =
            (nfloat4*)(order + ((size_t)plane * NPIX + (size_t)t * RPT * WO) * KK);
        const nfloat4* __restrict__ lb = (const nfloat4*)lorder;
#pragma unroll
        for (int i = tid; i < RPT * WO * KK / 4; i += BLK)  // 504 float4
            __builtin_nontemporal_store(lb[i], ob + i);

        // ---- Stage tile t+1 into the other buffer (vmcnt wait lands here).
        if (t + 1 < NT && stager) {
            float* dst = &lx[(t + 1) & 1][sr * LROW + 1 + 4 * scc];
            dst[0] = nval.x; dst[1] = nval.y; dst[2] = nval.z; dst[3] = nval.w;
        }
        __syncthreads();   // B: next buffer ready; lorder reads drained
    }
}

extern "C" void kernel_launch(void* const* d_in, const int* in_sizes, int n_in,
                              void* d_out, int out_size, void* d_ws, size_t ws_size,
                              hipStream_t stream) {
    const float* x = (const float*)d_in[0];
    const float* s = (const float*)d_in[1];
    float* out   = (float*)d_out;
    float* order = out + (size_t)B * C * NPIX;   // second output, flat after first

    dim3 grid(B * C);                            // 2048 blocks = 8/CU exactly
    rrsvm_kernel<<<grid, dim3(BLK), 0, stream>>>(x, s, out, order);
}

// Round 2
// 313.252 us; speedup vs baseline: 1.0849x; 1.0849x over previous
//
#include <hip/hip_runtime.h>

// RRSVM rank-weighted pooling, 3x3 / stride 2 / pad 1.
// x: [B=32, C=64, H=112, W=112] fp32;  s: [C, 3, 3] fp32
// out0: [B,C,56,56] fp32 ; out1: order [B,C,56,56,9] written as fp32.
//
// R7 = R5 (best verified, 313us) + deferred out-store.
// R6 post-mortem: __syncthreads drains vmcnt(0) INCLUDING nontemporal
// store acks; the persistent-loop version paid that drain 14x/block and
// regressed. R5 paid it once (out-store issued before the lorder
// barrier). R7 moves the out-store after the final barrier so no store
// is ever on the waited side of a barrier; waves end via s_endpgm with
// stores still in flight. Also: CE uses fmax/fmin for the value path
// (saves 2 cndmasks per CE).

typedef float nfloat4 __attribute__((ext_vector_type(4)));

constexpr int B  = 32;
constexpr int C  = 64;
constexpr int H  = 112;
constexpr int W  = 112;
constexpr int HO = 56;
constexpr int WO = 56;
constexpr int KK = 9;
constexpr int NPIX = HO * WO;          // 3136 windows per (b,c) plane
constexpr int BLK  = 256;
constexpr int LROW = 128;              // LDS row stride (floats)
constexpr int RPT  = 4;                // window-rows per block
constexpr int IR   = 2 * RPT + 1;      // input rows staged = 9

__global__ __launch_bounds__(BLK) void rrsvm_kernel(
    const float* __restrict__ x, const float* __restrict__ s,
    float* __restrict__ out, float* __restrict__ order)
{
    __shared__ float lx[IR * LROW];            // 4608 B
    __shared__ float lorder[RPT * WO * KK];    // 8064 B

    const int plane = blockIdx.y;              // b*C + c (block-uniform)
    const int ho0   = blockIdx.x;              // tile of 4 window-rows
    const int tid   = threadIdx.x;
    const int w     = tid >> 6;                // wave id 0..3 -> window-row
    const int lane  = tid & 63;                // lane -> window-col (56 live)
    const int c     = plane & (C - 1);

    const float* xp = x + (size_t)plane * (H * W);

    // ---- Stage 9 input rows (global rows 8*ho0-1 .. 8*ho0+7), shifted +1
    // in LDS so logical col -1 lands on the zeroed entry 0.
    if (tid < IR * (W / 4)) {                  // 252 float4 tasks
        const int r  = tid / (W / 4);          // 0..8
        const int cc = tid - r * (W / 4);      // 0..27
        const int grow = 8 * ho0 - 1 + r;      // -1..111
        nfloat4 val = (nfloat4)0.0f;
        if ((unsigned)grow < (unsigned)H)      // only ho0==0, r==0 is OOB
            val = *(const nfloat4*)(xp + grow * W + 4 * cc);
        float* dst = &lx[r * LROW + 1 + 4 * cc];
        dst[0] = val.x; dst[1] = val.y; dst[2] = val.z; dst[3] = val.w;
    }
    if (tid < IR) lx[tid * LROW] = 0.0f;       // logical col -1 = pad zero
    __syncthreads();

    // ---- Gather window from LDS.
    const bool live = (lane < WO);
    const int  lc   = live ? lane : 0;
    const int  ho   = ho0 * RPT + w;

    float v[KK];
    float fid[KK];
#pragma unroll
    for (int dy = 0; dy < 3; ++dy)
#pragma unroll
        for (int dx = 0; dx < 3; ++dx) {
            const int k = dy * 3 + dx;
            v[k]   = lx[(2 * w + dy) * LROW + 2 * lc + dx];
            fid[k] = (float)k;                 // compile-time constant
        }

    // ---- Sort descending by value; exact tie -> smaller index first.
    // (ids as floats: comparison exact for 0..8.)  Value path via
    // fmax/fmin (no NaNs in input); id path needs the full predicate.
    auto CE = [&](int a, int b) {
        const float va = v[a],   vb = v[b];
        const float fa = fid[a], fb = fid[b];
        const bool sw = (va < vb) || ((va == vb) && (fa > fb));
        v[a]   = fmaxf(va, vb);
        v[b]   = fminf(va, vb);
        fid[a] = sw ? fb : fa;
        fid[b] = sw ? fa : fb;
    };
    // Batcher odd-even mergesort on 0..7 (19 CEs) + insertion of 8 (8 CEs).
    CE(0,1); CE(2,3); CE(4,5); CE(6,7);
    CE(0,2); CE(1,3); CE(4,6); CE(5,7);
    CE(1,2); CE(5,6);
    CE(0,4); CE(1,5); CE(2,6); CE(3,7);
    CE(2,4); CE(3,5);
    CE(1,2); CE(3,4); CE(5,6);
    CE(7,8); CE(6,7); CE(5,6); CE(4,5); CE(3,4); CE(2,3); CE(1,2); CE(0,1);

    // ---- Weighted sum with per-channel rank weights (block-uniform c).
    const float* sc = s + c * KK;
    float acc = 0.0f;
#pragma unroll
    for (int k = 0; k < KK; ++k) acc = fmaf(v[k], sc[k], acc);

    if (live) {
        const int widx = w * WO + lane;        // window within tile, 0..223
#pragma unroll
        for (int k = 0; k < KK; ++k)
            lorder[widx * KK + k] = fid[k];    // stride 9 -> 2-way, free
    }
    __syncthreads();   // drains lgkm only: no vmem store issued yet

    // ---- All stores AFTER the last barrier: never waited on (s_endpgm
    // does not drain the store queue).
    nfloat4* __restrict__ ob =
        (nfloat4*)(order + ((size_t)plane * NPIX + (size_t)ho0 * RPT * WO) * KK);
    const nfloat4* __restrict__ lb = (const nfloat4*)lorder;
#pragma unroll
    for (int i = tid; i < RPT * WO * KK / 4; i += BLK)  // 504 float4
        __builtin_nontemporal_store(lb[i], ob + i);

    if (live)
        __builtin_nontemporal_store(acc, out + (size_t)plane * NPIX + ho * WO + lane);
}

extern "C" void kernel_launch(void* const* d_in, const int* in_sizes, int n_in,
                              void* d_out, int out_size, void* d_ws, size_t ws_size,
                              hipStream_t stream) {
    const float* x = (const float*)d_in[0];
    const float* s = (const float*)d_in[1];
    float* out   = (float*)d_out;
    float* order = out + (size_t)B * C * NPIX;   // second output, flat after first

    dim3 grid(HO / RPT, B * C);                  // (14, 2048)
    rrsvm_kernel<<<grid, dim3(BLK), 0, stream>>>(x, s, out, order);
}